// Round 10
// baseline (155.172 us; speedup 1.0000x reference)
//
#include <hip/hip_runtime.h>
#include <hip/hip_cooperative_groups.h>
#include <hip/hip_bf16.h>
#include <math.h>

namespace cg = cooperative_groups;

#define NSEQ 512
#define EMB 256

typedef __attribute__((ext_vector_type(8))) short bf16x8;
typedef __attribute__((ext_vector_type(4))) float f32x4;

__device__ __forceinline__ unsigned short f2bf(float f) {
    unsigned u = __float_as_uint(f);
    unsigned r = (u + 0x7FFFu + ((u >> 16) & 1u)) >> 16;
    return (unsigned short)r;
}
__device__ __forceinline__ float bf2f(unsigned short s) {
    return __uint_as_float(((unsigned)s) << 16);
}
__device__ __forceinline__ ushort4 cvt4(float4 v) {
    ushort4 o;
    o.x = f2bf(v.x); o.y = f2bf(v.y); o.z = f2bf(v.z); o.w = f2bf(v.w);
    return o;
}

// LDS union across phases (max = P1's 68.6 KB, proven size in r7/r9)
struct P1s {
    unsigned short Xs[64 * 264];
    unsigned short Ws[64 * 264];
    float red[4][64];
};
struct P2s {
    unsigned short Plds[4][16][136];
    float Olds[4][16][33];
    float mlds[4][16], llds[4][16];
    float scl[4][16], Li[16];
    float qadd[32];
};
struct P3s {
    unsigned short As_[64 * 72];
    unsigned short Bs_[64 * 72];
};
struct P4s { float red[4][4][2]; };
union SMemU { P1s p1; P2s p2; P3s p3; P4s p4; };

// Single cooperative kernel: 256 blocks x 256 threads, 5 phases, 4 grid syncs.
// P0 cvt -> P1 proj GEMM (+maxPart) -> P2 flash attn (2 jobs/blk)
//  -> P3 split-K ogemm -> P4 residual+LN+LN.
__global__ __launch_bounds__(256) void k_mega(
    const float* __restrict__ X,
    const float* __restrict__ Wq, const float* __restrict__ Wk,
    const float* __restrict__ Wv, const float* __restrict__ Wr,
    const float* __restrict__ Wo,
    const float* __restrict__ bq, const float* __restrict__ bv,
    const float* __restrict__ br, const float* __restrict__ bo,
    const float* __restrict__ g1, const float* __restrict__ b1,
    const float* __restrict__ g2, const float* __restrict__ b2,
    unsigned short* __restrict__ Xb, unsigned short* __restrict__ Wallb,
    unsigned short* __restrict__ Wob,
    unsigned short* __restrict__ Qb, unsigned short* __restrict__ Kb,
    unsigned short* __restrict__ Vtb, unsigned short* __restrict__ attnb,
    float* __restrict__ maxPart, float* __restrict__ yP,
    float* __restrict__ out)
{
    cg::grid_group grid = cg::this_grid();
    __shared__ __align__(16) SMemU sm;

    const int t = threadIdx.x;
    const int bid = blockIdx.x;       // 0..255
    const int w = t >> 6, l = t & 63;
    const int ln = l & 15, kg = l >> 4;
    const float scale = 0.17677669529663687f;  // 1/sqrt(32)

    // ---------------- P0: fp32 -> bf16 conversions ----------------
    {
        const int idx = bid * 256 + t;          // float4 index 0..65535
        ((ushort4*)Xb)[idx] = cvt4(((const float4*)X)[idx]);

        int row = idx >> 6, c4 = idx & 63;      // Wall row 0..1023
        int seg = row >> 8, wr = row & 255;
        size_t off = (size_t)wr * 64 + c4;
        float4 wv;
        if (seg == 0) {
            float4 a = ((const float4*)Wq)[off], r = ((const float4*)Wr)[off];
            wv = make_float4(a.x - r.x, a.y - r.y, a.z - r.z, a.w - r.w);
        } else if (seg == 1) {
            float4 a = ((const float4*)Wk)[off], r = ((const float4*)Wr)[off];
            wv = make_float4(a.x + r.x, a.y + r.y, a.z + r.z, a.w + r.w);
        } else if (seg == 2) {
            wv = ((const float4*)Wv)[off];
        } else {
            wv = ((const float4*)Wr)[off];
        }
        ((ushort4*)Wallb)[idx] = cvt4(wv);

        if (bid < 64) {
            int j = bid * 256 + t;              // Wo: 16384 float4
            ((ushort4*)Wob)[j] = cvt4(((const float4*)Wo)[j]);
        }
    }
    grid.sync();

    // ---------------- P1: projection GEMM (256 jobs) ----------------
    // job = bid: m = bid&15 (64-row tile), y = bid>>4: seg = y>>2, nW = y*64
    {
        const int m0 = (bid & 15) * 64;
        const int y  = bid >> 4;
        const int nW = y * 64;
        const int seg = y >> 2;

        const uint4* Xg = (const uint4*)Xb;     // [1024][32]
        const uint4* Wg = (const uint4*)Wallb;
        #pragma unroll
        for (int i = 0; i < 8; ++i) {
            int idx = i * 256 + t;              // 0..2047
            int row = idx >> 5, c8 = idx & 31;
            *(uint4*)(sm.p1.Xs + row * 264 + c8 * 8) = Xg[(size_t)(m0 + row) * 32 + c8];
            *(uint4*)(sm.p1.Ws + row * 264 + c8 * 8) = Wg[(size_t)(nW + row) * 32 + c8];
        }
        __syncthreads();

        f32x4 acc[4] = {{0.f,0.f,0.f,0.f},{0.f,0.f,0.f,0.f},
                        {0.f,0.f,0.f,0.f},{0.f,0.f,0.f,0.f}};
        const int arow = (w << 4) + ln;
        #pragma unroll
        for (int ks = 0; ks < 8; ++ks) {
            bf16x8 a = *(const bf16x8*)(sm.p1.Xs + arow * 264 + ks * 32 + kg * 8);
            #pragma unroll
            for (int nf = 0; nf < 4; ++nf) {
                bf16x8 b = *(const bf16x8*)(sm.p1.Ws + (nf * 16 + ln) * 264 + ks * 32 + kg * 8);
                acc[nf] = __builtin_amdgcn_mfma_f32_16x16x32_bf16(a, b, acc[nf], 0, 0, 0);
            }
        }

        if (seg == 0) {
            #pragma unroll
            for (int nf = 0; nf < 4; ++nf) {
                int c = (nW & 255) + nf * 16 + ln;
                float bb = bq[c];
                #pragma unroll
                for (int r = 0; r < 4; ++r) {
                    int row = m0 + w * 16 + kg * 4 + r;
                    Qb[(size_t)row * 256 + c] = f2bf(acc[nf][r] + bb);
                }
            }
        } else if (seg == 1) {
            #pragma unroll
            for (int nf = 0; nf < 4; ++nf) {
                int c = (nW & 255) + nf * 16 + ln;
                #pragma unroll
                for (int r = 0; r < 4; ++r) {
                    int row = m0 + w * 16 + kg * 4 + r;
                    Kb[(size_t)row * 256 + c] = f2bf(acc[nf][r]);
                }
            }
        } else if (seg == 2) {
            #pragma unroll
            for (int nf = 0; nf < 4; ++nf) {
                int c = (nW & 255) + nf * 16 + ln;
                int h = c >> 5, d = c & 31;
                float bb = bv[c];
                #pragma unroll
                for (int r = 0; r < 4; ++r) {
                    int row = m0 + w * 16 + kg * 4 + r;
                    int bz = row >> 9, ml = row & 511;
                    Vtb[((size_t)(bz * 8 + h) * 32 + d) * 512 + ml] = f2bf(acc[nf][r] + bb);
                }
            }
        } else {
            #pragma unroll
            for (int nf = 0; nf < 4; ++nf) {
                float mx = fmaxf(fmaxf(acc[nf][0], acc[nf][1]),
                                 fmaxf(acc[nf][2], acc[nf][3]));
                mx = fmaxf(mx, __shfl_xor(mx, 16));
                mx = fmaxf(mx, __shfl_xor(mx, 32));
                if (l < 16) sm.p1.red[w][nf * 16 + ln] = mx;
            }
            __syncthreads();
            if (t < 64) {
                float m = fmaxf(fmaxf(sm.p1.red[0][t], sm.p1.red[1][t]),
                                fmaxf(sm.p1.red[2][t], sm.p1.red[3][t]));
                const int bz = (bid & 15) >> 3;
                const int mblk = bid & 7;
                maxPart[bz * 2048 + mblk * 256 + (nW & 255) + t] = m;
            }
        }
    }
    grid.sync();

    // ---------------- P2: flash attention (512 jobs, 2 per block) ----------------
    for (int jj = 0; jj < 2; ++jj) {
        const int j = bid * 2 + jj;
        const int q0 = (j & 31) * 16;
        const int h = (j >> 5) & 7, bz = j >> 8;
        const int e0 = h * 32;
        const int bh = bz * 8 + h;

        __syncthreads();   // LDS reuse guard between jobs / phases
        if (t < 32) {
            float m = maxPart[bz * 2048 + e0 + t];
            #pragma unroll
            for (int p = 1; p < 8; ++p)
                m = fmaxf(m, maxPart[bz * 2048 + p * 256 + e0 + t]);
            sm.p2.qadd[t] = m + br[e0 + t];
        }
        __syncthreads();

        // a-frag: Qr = (Qb + maxP + br) * scale
        bf16x8 af;
        {
            size_t qrow = (size_t)(bz * NSEQ + q0 + ln) * 256 + e0 + kg * 8;
            bf16x8 qa = *(const bf16x8*)(Qb + qrow);
            #pragma unroll
            for (int jx = 0; jx < 8; ++jx) {
                int d = kg * 8 + jx;
                af[jx] = (short)f2bf((bf2f((unsigned short)qa[jx]) + sm.p2.qadd[d]) * scale);
            }
        }

        // QK^T: this wave's 128 keys
        const int key0 = w * 128;
        f32x4 sc[8];
        #pragma unroll
        for (int kf = 0; kf < 8; ++kf) {
            size_t krow = (size_t)(bz * NSEQ + key0 + kf * 16 + ln) * 256 + e0 + kg * 8;
            bf16x8 bfr = *(const bf16x8*)(Kb + krow);
            f32x4 z = {0.f, 0.f, 0.f, 0.f};
            sc[kf] = __builtin_amdgcn_mfma_f32_16x16x32_bf16(af, bfr, z, 0, 0, 0);
        }

        // single-pass softmax over 128 keys; lane owns q = kg*4+r
        float m_[4], l_[4];
        #pragma unroll
        for (int r = 0; r < 4; ++r) {
            float mx = sc[0][r];
            #pragma unroll
            for (int kf = 1; kf < 8; ++kf) mx = fmaxf(mx, sc[kf][r]);
            #pragma unroll
            for (int off = 1; off < 16; off <<= 1) mx = fmaxf(mx, __shfl_xor(mx, off));
            m_[r] = mx;
            float s = 0.f;
            #pragma unroll
            for (int kf = 0; kf < 8; ++kf) {
                float p = __expf(sc[kf][r] - mx);
                sc[kf][r] = p;
                s += p;
            }
            #pragma unroll
            for (int off = 1; off < 16; off <<= 1) s += __shfl_xor(s, off);
            l_[r] = s;
        }

        // P -> LDS (bf16), wave-private
        #pragma unroll
        for (int kf = 0; kf < 8; ++kf)
            #pragma unroll
            for (int r = 0; r < 4; ++r)
                sm.p2.Plds[w][kg * 4 + r][kf * 16 + ln] = f2bf(sc[kf][r]);

        // PV
        f32x4 o[2] = {{0.f,0.f,0.f,0.f},{0.f,0.f,0.f,0.f}};
        #pragma unroll
        for (int ks = 0; ks < 4; ++ks) {
            bf16x8 pf = *(const bf16x8*)&sm.p2.Plds[w][ln][ks * 32 + kg * 8];
            #pragma unroll
            for (int df = 0; df < 2; ++df) {
                size_t vrow = ((size_t)bh * 32 + df * 16 + ln) * 512 + key0 + ks * 32 + kg * 8;
                bf16x8 vf = *(const bf16x8*)(Vtb + vrow);
                o[df] = __builtin_amdgcn_mfma_f32_16x16x32_bf16(pf, vf, o[df], 0, 0, 0);
            }
        }

        if (ln == 0) {
            #pragma unroll
            for (int r = 0; r < 4; ++r) {
                sm.p2.mlds[w][kg * 4 + r] = m_[r];
                sm.p2.llds[w][kg * 4 + r] = l_[r];
            }
        }
        #pragma unroll
        for (int df = 0; df < 2; ++df)
            #pragma unroll
            for (int r = 0; r < 4; ++r)
                sm.p2.Olds[w][kg * 4 + r][df * 16 + ln] = o[df][r];
        __syncthreads();

        if (t < 16) {
            float M = fmaxf(fmaxf(sm.p2.mlds[0][t], sm.p2.mlds[1][t]),
                            fmaxf(sm.p2.mlds[2][t], sm.p2.mlds[3][t]));
            float L = 0.f;
            #pragma unroll
            for (int wv = 0; wv < 4; ++wv) {
                float s = __expf(sm.p2.mlds[wv][t] - M);
                sm.p2.scl[wv][t] = s;
                L += s * sm.p2.llds[wv][t];
            }
            sm.p2.Li[t] = 1.f / L;
        }
        __syncthreads();

        #pragma unroll
        for (int i = 0; i < 2; ++i) {
            int idx = t + 256 * i;
            int q = idx >> 5, d = idx & 31;
            float acc = 0.f;
            #pragma unroll
            for (int wv = 0; wv < 4; ++wv)
                acc += sm.p2.scl[wv][q] * sm.p2.Olds[wv][q][d];
            attnb[(size_t)(bz * NSEQ + q0 + q) * 256 + e0 + d] = f2bf(acc * sm.p2.Li[q]);
        }
    }
    grid.sync();

    // ---------------- P3: out-projection split-K=4 (256 jobs) ----------------
    {
        const int m0 = (bid & 15) * 64;
        const int n0 = ((bid >> 4) & 3) * 64;
        const int kz = bid >> 6;

        const uint4* Ag = (const uint4*)attnb;  // [1024][32]
        const uint4* Wg = (const uint4*)Wob;    // [256][32]
        #pragma unroll
        for (int i = 0; i < 2; ++i) {
            int idx = i * 256 + t;              // 0..511
            int row = idx >> 3, c8 = idx & 7;
            *(uint4*)(sm.p3.As_ + row * 72 + c8 * 8) = Ag[(size_t)(m0 + row) * 32 + kz * 8 + c8];
            *(uint4*)(sm.p3.Bs_ + row * 72 + c8 * 8) = Wg[(size_t)(n0 + row) * 32 + kz * 8 + c8];
        }
        __syncthreads();

        f32x4 acc[4] = {{0.f,0.f,0.f,0.f},{0.f,0.f,0.f,0.f},
                        {0.f,0.f,0.f,0.f},{0.f,0.f,0.f,0.f}};
        const int arow = (w << 4) + ln;
        #pragma unroll
        for (int ks = 0; ks < 2; ++ks) {
            bf16x8 a = *(const bf16x8*)(sm.p3.As_ + arow * 72 + ks * 32 + kg * 8);
            #pragma unroll
            for (int nf = 0; nf < 4; ++nf) {
                bf16x8 b = *(const bf16x8*)(sm.p3.Bs_ + (nf * 16 + ln) * 72 + ks * 32 + kg * 8);
                acc[nf] = __builtin_amdgcn_mfma_f32_16x16x32_bf16(a, b, acc[nf], 0, 0, 0);
            }
        }

        float* dst = yP + (size_t)kz * (1024 * 256);
        #pragma unroll
        for (int nf = 0; nf < 4; ++nf) {
            #pragma unroll
            for (int r = 0; r < 4; ++r) {
                int row = m0 + w * 16 + kg * 4 + r;
                dst[(size_t)row * 256 + n0 + nf * 16 + ln] = acc[nf][r];
            }
        }
    }
    grid.sync();

    // ---------------- P4: residual + LN1 + LN2 (256 jobs of 4 rows) ----------------
    {
        __syncthreads();   // LDS reuse guard
        const int r0 = bid * 4;
        const int c = t;
        const int wid = t >> 6, lane = t & 63;

        float y[4];
        #pragma unroll
        for (int r = 0; r < 4; ++r) {
            size_t off = (size_t)(r0 + r) * 256 + c;
            y[r] = X[off] + bo[c] + yP[off] + yP[262144 + off]
                 + yP[524288 + off] + yP[786432 + off];
        }

        #pragma unroll
        for (int r = 0; r < 4; ++r) {
            float s = y[r], s2 = y[r] * y[r];
            #pragma unroll
            for (int off = 32; off > 0; off >>= 1) {
                s  += __shfl_xor(s, off);
                s2 += __shfl_xor(s2, off);
            }
            if (lane == 0) { sm.p4.red[wid][r][0] = s; sm.p4.red[wid][r][1] = s2; }
        }
        __syncthreads();
        float t1[4];
        #pragma unroll
        for (int r = 0; r < 4; ++r) {
            float s  = sm.p4.red[0][r][0] + sm.p4.red[1][r][0] + sm.p4.red[2][r][0] + sm.p4.red[3][r][0];
            float s2 = sm.p4.red[0][r][1] + sm.p4.red[1][r][1] + sm.p4.red[2][r][1] + sm.p4.red[3][r][1];
            float mu = s * (1.f / 256.f);
            float var = s2 * (1.f / 256.f) - mu * mu;
            float rs = rsqrtf(var + 1e-5f);
            t1[r] = (y[r] - mu) * rs * g1[c] + b1[c];
        }
        __syncthreads();

        #pragma unroll
        for (int r = 0; r < 4; ++r) {
            float s = t1[r], s2 = t1[r] * t1[r];
            #pragma unroll
            for (int off = 32; off > 0; off >>= 1) {
                s  += __shfl_xor(s, off);
                s2 += __shfl_xor(s2, off);
            }
            if (lane == 0) { sm.p4.red[wid][r][0] = s; sm.p4.red[wid][r][1] = s2; }
        }
        __syncthreads();
        #pragma unroll
        for (int r = 0; r < 4; ++r) {
            float s  = sm.p4.red[0][r][0] + sm.p4.red[1][r][0] + sm.p4.red[2][r][0] + sm.p4.red[3][r][0];
            float s2 = sm.p4.red[0][r][1] + sm.p4.red[1][r][1] + sm.p4.red[2][r][1] + sm.p4.red[3][r][1];
            float mu = s * (1.f / 256.f);
            float var = s2 * (1.f / 256.f) - mu * mu;
            float rs = rsqrtf(var + 1e-5f);
            out[(size_t)(r0 + r) * 256 + c] = (t1[r] - mu) * rs * g2[c] + b2[c];
        }
    }
}

extern "C" void kernel_launch(void* const* d_in, const int* in_sizes, int n_in,
                              void* d_out, int out_size, void* d_ws, size_t ws_size,
                              hipStream_t stream)
{
    const float* X  = (const float*)d_in[0];
    const float* Wq = (const float*)d_in[1];
    const float* bq = (const float*)d_in[2];
    const float* Wk = (const float*)d_in[3];
    const float* bk = (const float*)d_in[4];   // cancels in softmax (unused)
    const float* Wv = (const float*)d_in[5];
    const float* bv = (const float*)d_in[6];
    const float* Wr = (const float*)d_in[7];
    const float* br = (const float*)d_in[8];
    const float* Wo = (const float*)d_in[9];
    const float* bo = (const float*)d_in[10];
    const float* g1 = (const float*)d_in[11];
    const float* b1 = (const float*)d_in[12];
    const float* g2 = (const float*)d_in[13];
    const float* b2 = (const float*)d_in[14];
    float* out = (float*)d_out;
    (void)bk;

    unsigned short* u = (unsigned short*)d_ws;
    unsigned short* Xb    = u;               // 1024*256
    unsigned short* Wallb = u + 262144;      // 1024*256
    unsigned short* Wob   = u + 524288;      // 256*256
    unsigned short* Qb    = u + 589824;      // 1024*256
    unsigned short* Kb    = u + 851968;      // 1024*256
    unsigned short* Vtb   = u + 1114112;     // 16*32*512
    unsigned short* attnb = u + 1376256;     // 1024*256
    float* maxPart = (float*)(u + 1638400);  // [2][8][256]
    float* yP      = (float*)(u + 1646592);  // 4*1024*256 fp32

    void* args[] = {
        (void*)&X, (void*)&Wq, (void*)&Wk, (void*)&Wv, (void*)&Wr, (void*)&Wo,
        (void*)&bq, (void*)&bv, (void*)&br, (void*)&bo,
        (void*)&g1, (void*)&b1, (void*)&g2, (void*)&b2,
        (void*)&Xb, (void*)&Wallb, (void*)&Wob,
        (void*)&Qb, (void*)&Kb, (void*)&Vtb, (void*)&attnb,
        (void*)&maxPart, (void*)&yP, (void*)&out
    };
    hipLaunchCooperativeKernel((const void*)k_mega, dim3(256), dim3(256),
                               args, 0, stream);
}

// Round 11
// 27.096 us; speedup vs baseline: 5.7268x; 5.7268x over previous
//
#include <hip/hip_runtime.h>
#include <hip/hip_bf16.h>
#include <math.h>

#define NSEQ 512
#define EMB 256

typedef __attribute__((ext_vector_type(8))) short bf16x8;
typedef __attribute__((ext_vector_type(4))) float f32x4;

__device__ __forceinline__ unsigned short f2bf(float f) {
    unsigned u = __float_as_uint(f);
    unsigned r = (u + 0x7FFFu + ((u >> 16) & 1u)) >> 16;
    return (unsigned short)r;
}
__device__ __forceinline__ float bf2f(unsigned short s) {
    return __uint_as_float(((unsigned)s) << 16);
}
__device__ __forceinline__ ushort4 cvt4(float4 v) {
    ushort4 o;
    o.x = f2bf(v.x); o.y = f2bf(v.y); o.z = f2bf(v.z); o.w = f2bf(v.w);
    return o;
}

// K1: projections via bf16 MFMA, fp32 sources converted during LDS staging.
//   blockIdx.y 0..15: seg = y>>2 (0:Q' 1:K' 2:V 3:P), wbase = (y&3)*64
//     seg0: Qb = bf16(X(Wq-Wr)^T + bq)
//     seg1: Kb = bf16(X(Wk+Wr)^T)            (K-side bias cancels in softmax)
//     seg2: Vtb[16][32][512] = bf16(XWv^T + bv) transposed per (b,h)
//     seg3: P = XWr^T -> per-block 64-row max -> maxPart (private slot, no atomics)
//   blockIdx.y == 16: convert Wo fp32 -> Wob bf16 (piggyback)
// grid (16, 17) x 256 (4 waves). [r9-proven]
__global__ __launch_bounds__(256) void k_gemm_mfma(
    const float* __restrict__ X,
    const float* __restrict__ Wq, const float* __restrict__ Wk,
    const float* __restrict__ Wv, const float* __restrict__ Wr,
    const float* __restrict__ Wo,
    const float* __restrict__ bq, const float* __restrict__ bv,
    unsigned short* __restrict__ Qb, unsigned short* __restrict__ Kb,
    unsigned short* __restrict__ Vtb, unsigned short* __restrict__ Wob,
    float* __restrict__ maxPart)   // [2][8][256]
{
    const int t = threadIdx.x;

    if (blockIdx.y == 16) {   // Wo fp32 -> bf16
        const float4* Wg = (const float4*)Wo;
        #pragma unroll
        for (int i = 0; i < 4; ++i) {
            int idx4 = blockIdx.x * 1024 + i * 256 + t;   // 0..16383
            ((ushort4*)Wob)[idx4] = cvt4(Wg[idx4]);
        }
        return;
    }

    __shared__ __align__(16) unsigned short Xs[64 * 264];  // stride 264 bf16 = 528B
    __shared__ __align__(16) unsigned short Ws[64 * 264];
    __shared__ float red[4][64];

    const int w = t >> 6, l = t & 63;
    const int ln = l & 15, kg = l >> 4;
    const int m0 = blockIdx.x * 64;
    const int nW = blockIdx.y * 64;
    const int seg = blockIdx.y >> 2;
    const int wbase = (blockIdx.y & 3) * 64;

    const float4* X4  = (const float4*)X;     // [1024][64] float4
    const float4* Wq4 = (const float4*)Wq;
    const float4* Wk4 = (const float4*)Wk;
    const float4* Wv4 = (const float4*)Wv;
    const float4* Wr4 = (const float4*)Wr;

    #pragma unroll
    for (int i = 0; i < 16; ++i) {
        int idx = i * 256 + t;                // float4 index 0..4095
        int row = idx >> 6, c4 = idx & 63;
        float4 xv = X4[(size_t)(m0 + row) * 64 + c4];
        *(ushort4*)(Xs + row * 264 + c4 * 4) = cvt4(xv);

        size_t off = (size_t)(wbase + row) * 64 + c4;
        float4 wv;
        if (seg == 0) {
            float4 a = Wq4[off], r = Wr4[off];
            wv = make_float4(a.x - r.x, a.y - r.y, a.z - r.z, a.w - r.w);
        } else if (seg == 1) {
            float4 a = Wk4[off], r = Wr4[off];
            wv = make_float4(a.x + r.x, a.y + r.y, a.z + r.z, a.w + r.w);
        } else if (seg == 2) {
            wv = Wv4[off];
        } else {
            wv = Wr4[off];
        }
        *(ushort4*)(Ws + row * 264 + c4 * 4) = cvt4(wv);
    }
    __syncthreads();

    f32x4 acc[4] = {{0.f,0.f,0.f,0.f},{0.f,0.f,0.f,0.f},
                    {0.f,0.f,0.f,0.f},{0.f,0.f,0.f,0.f}};
    const int arow = (w << 4) + ln;
    #pragma unroll
    for (int ks = 0; ks < 8; ++ks) {
        bf16x8 a = *(const bf16x8*)(Xs + arow * 264 + ks * 32 + kg * 8);
        #pragma unroll
        for (int nf = 0; nf < 4; ++nf) {
            bf16x8 b = *(const bf16x8*)(Ws + (nf * 16 + ln) * 264 + ks * 32 + kg * 8);
            acc[nf] = __builtin_amdgcn_mfma_f32_16x16x32_bf16(a, b, acc[nf], 0, 0, 0);
        }
    }

    if (seg == 0) {
        #pragma unroll
        for (int nf = 0; nf < 4; ++nf) {
            int c = (nW & 255) + nf * 16 + ln;
            float bb = bq[c];
            #pragma unroll
            for (int r = 0; r < 4; ++r) {
                int row = m0 + w * 16 + kg * 4 + r;
                Qb[(size_t)row * 256 + c] = f2bf(acc[nf][r] + bb);
            }
        }
    } else if (seg == 1) {
        #pragma unroll
        for (int nf = 0; nf < 4; ++nf) {
            int c = (nW & 255) + nf * 16 + ln;
            #pragma unroll
            for (int r = 0; r < 4; ++r) {
                int row = m0 + w * 16 + kg * 4 + r;
                Kb[(size_t)row * 256 + c] = f2bf(acc[nf][r]);
            }
        }
    } else if (seg == 2) {
        #pragma unroll
        for (int nf = 0; nf < 4; ++nf) {
            int c = (nW & 255) + nf * 16 + ln;
            int h = c >> 5, d = c & 31;
            float bb = bv[c];
            #pragma unroll
            for (int r = 0; r < 4; ++r) {
                int row = m0 + w * 16 + kg * 4 + r;
                int b = row >> 9, ml = row & 511;
                Vtb[((size_t)(b * 8 + h) * 32 + d) * 512 + ml] = f2bf(acc[nf][r] + bb);
            }
        }
    } else {
        #pragma unroll
        for (int nf = 0; nf < 4; ++nf) {
            float mx = fmaxf(fmaxf(acc[nf][0], acc[nf][1]),
                             fmaxf(acc[nf][2], acc[nf][3]));
            mx = fmaxf(mx, __shfl_xor(mx, 16));
            mx = fmaxf(mx, __shfl_xor(mx, 32));
            if (l < 16) red[w][nf * 16 + ln] = mx;
        }
        __syncthreads();
        if (t < 64) {
            float m = fmaxf(fmaxf(red[0][t], red[1][t]),
                            fmaxf(red[2][t], red[3][t]));
            const int b = blockIdx.x >> 3;
            const int mblk = blockIdx.x & 7;
            maxPart[b * 2048 + mblk * 256 + (nW & 255) + t] = m;
        }
    }
}

// K2: MFMA flash attention, 32-row q-tiles. grid (16, 8, 2) x 256 (4 waves).
// Wave w: keys w*128..+127, single-pass softmax, 2 q-frags (rows q0..+15, +16..+31).
// K/Vt frags direct from global (L2); K/V traffic halved vs 16-row tiles.
__global__ __launch_bounds__(256) void k_attn_mfma(
    const unsigned short* __restrict__ Qb,   // [1024][256] bf16
    const unsigned short* __restrict__ Kb,   // [1024][256] bf16
    const unsigned short* __restrict__ Vtb,  // [16][32][512] bf16
    const float* __restrict__ maxPart,       // [2][8][256]
    const float* __restrict__ br,
    unsigned short* __restrict__ attnb)      // [1024][256] bf16
{
    __shared__ __align__(16) unsigned short Plds[4][32][136];
    __shared__ float Olds[4][32][33];
    __shared__ float mlds[4][32], llds[4][32];
    __shared__ float scl[4][32], Li[32];
    __shared__ float qadd[32];

    const int t = threadIdx.x;
    const int w = t >> 6, l = t & 63;
    const int ln = l & 15, kg = l >> 4;
    const int q0 = blockIdx.x * 32;
    const int h = blockIdx.y, bz = blockIdx.z;
    const int e0 = h * 32;
    const int bh = bz * 8 + h;
    const float scale = 0.17677669529663687f;  // 1/sqrt(32)

    if (t < 32) {
        float m = maxPart[bz * 2048 + e0 + t];
        #pragma unroll
        for (int j = 1; j < 8; ++j)
            m = fmaxf(m, maxPart[bz * 2048 + j * 256 + e0 + t]);
        qadd[t] = m + br[e0 + t];
    }
    __syncthreads();

    // a-frags: Qr = (Qb + maxP + br) * scale, re-rounded to bf16
    bf16x8 af[2];
    #pragma unroll
    for (int qf = 0; qf < 2; ++qf) {
        size_t qrow = (size_t)(bz * NSEQ + q0 + qf * 16 + ln) * 256 + e0 + kg * 8;
        bf16x8 qa = *(const bf16x8*)(Qb + qrow);
        #pragma unroll
        for (int j = 0; j < 8; ++j) {
            int d = kg * 8 + j;
            af[qf][j] = (short)f2bf((bf2f((unsigned short)qa[j]) + qadd[d]) * scale);
        }
    }

    // QK^T: 8 key-frags x 2 q-frags (8 K loads, 16 MFMAs)
    const int key0 = w * 128;
    f32x4 sc[2][8];
    #pragma unroll
    for (int kf = 0; kf < 8; ++kf) {
        size_t krow = (size_t)(bz * NSEQ + key0 + kf * 16 + ln) * 256 + e0 + kg * 8;
        bf16x8 bfr = *(const bf16x8*)(Kb + krow);
        f32x4 z = {0.f, 0.f, 0.f, 0.f};
        sc[0][kf] = __builtin_amdgcn_mfma_f32_16x16x32_bf16(af[0], bfr, z, 0, 0, 0);
        sc[1][kf] = __builtin_amdgcn_mfma_f32_16x16x32_bf16(af[1], bfr, z, 0, 0, 0);
    }

    // single-pass softmax over this wave's 128 keys; lane owns q = qf*16+kg*4+r
    float m_[2][4], l_[2][4];
    #pragma unroll
    for (int qf = 0; qf < 2; ++qf) {
        #pragma unroll
        for (int r = 0; r < 4; ++r) {
            float mx = sc[qf][0][r];
            #pragma unroll
            for (int kf = 1; kf < 8; ++kf) mx = fmaxf(mx, sc[qf][kf][r]);
            #pragma unroll
            for (int off = 1; off < 16; off <<= 1) mx = fmaxf(mx, __shfl_xor(mx, off));
            m_[qf][r] = mx;
            float s = 0.f;
            #pragma unroll
            for (int kf = 0; kf < 8; ++kf) {
                float p = __expf(sc[qf][kf][r] - mx);
                sc[qf][kf][r] = p;
                s += p;
            }
            #pragma unroll
            for (int off = 1; off < 16; off <<= 1) s += __shfl_xor(s, off);
            l_[qf][r] = s;
        }
    }

    // P -> LDS (bf16), wave-private
    #pragma unroll
    for (int qf = 0; qf < 2; ++qf)
        #pragma unroll
        for (int kf = 0; kf < 8; ++kf)
            #pragma unroll
            for (int r = 0; r < 4; ++r)
                Plds[w][qf * 16 + kg * 4 + r][kf * 16 + ln] = f2bf(sc[qf][kf][r]);

    // PV: O[32 q][32 d]; 8 V loads, 16 MFMAs
    f32x4 o[2][2] = {{{0.f,0.f,0.f,0.f},{0.f,0.f,0.f,0.f}},
                     {{0.f,0.f,0.f,0.f},{0.f,0.f,0.f,0.f}}};
    #pragma unroll
    for (int ks = 0; ks < 4; ++ks) {
        bf16x8 vf[2];
        #pragma unroll
        for (int df = 0; df < 2; ++df) {
            size_t vrow = ((size_t)bh * 32 + df * 16 + ln) * 512 + key0 + ks * 32 + kg * 8;
            vf[df] = *(const bf16x8*)(Vtb + vrow);
        }
        #pragma unroll
        for (int qf = 0; qf < 2; ++qf) {
            bf16x8 pf = *(const bf16x8*)&Plds[w][qf * 16 + ln][ks * 32 + kg * 8];
            o[qf][0] = __builtin_amdgcn_mfma_f32_16x16x32_bf16(pf, vf[0], o[qf][0], 0, 0, 0);
            o[qf][1] = __builtin_amdgcn_mfma_f32_16x16x32_bf16(pf, vf[1], o[qf][1], 0, 0, 0);
        }
    }

    // write per-wave partials
    if (ln == 0) {
        #pragma unroll
        for (int qf = 0; qf < 2; ++qf)
            #pragma unroll
            for (int r = 0; r < 4; ++r) {
                mlds[w][qf * 16 + kg * 4 + r] = m_[qf][r];
                llds[w][qf * 16 + kg * 4 + r] = l_[qf][r];
            }
    }
    #pragma unroll
    for (int qf = 0; qf < 2; ++qf)
        #pragma unroll
        for (int df = 0; df < 2; ++df)
            #pragma unroll
            for (int r = 0; r < 4; ++r)
                Olds[w][qf * 16 + kg * 4 + r][df * 16 + ln] = o[qf][df][r];
    __syncthreads();

    // combine scales per q (threads 0..31)
    if (t < 32) {
        float M = fmaxf(fmaxf(mlds[0][t], mlds[1][t]),
                        fmaxf(mlds[2][t], mlds[3][t]));
        float L = 0.f;
        #pragma unroll
        for (int wv = 0; wv < 4; ++wv) {
            float s = __expf(mlds[wv][t] - M);
            scl[wv][t] = s;
            L += s * llds[wv][t];
        }
        Li[t] = 1.f / L;
    }
    __syncthreads();

    // combine: 1024 outputs, 4 per thread
    #pragma unroll
    for (int i = 0; i < 4; ++i) {
        int idx = t + 256 * i;
        int q = idx >> 5, d = idx & 31;
        float acc = 0.f;
        #pragma unroll
        for (int wv = 0; wv < 4; ++wv)
            acc += scl[wv][q] * Olds[wv][q][d];
        attnb[(size_t)(bz * NSEQ + q0 + q) * 256 + e0 + d] = f2bf(acc * Li[q]);
    }
}

// K3: out-projection, bf16 MFMA, split-K=4, bf16 partials. grid (16,4,4) x 256.
__global__ __launch_bounds__(256) void k_ogemm_mfma(
    const unsigned short* __restrict__ Ab,   // attnb [1024][256] bf16
    const unsigned short* __restrict__ Wob,  // [256][256] bf16
    unsigned short* __restrict__ yPb)        // [4][1024][256] bf16
{
    __shared__ __align__(16) unsigned short As_[64 * 72];
    __shared__ __align__(16) unsigned short Bs_[64 * 72];

    const int t = threadIdx.x;
    const int w = t >> 6, l = t & 63;
    const int ln = l & 15, kg = l >> 4;
    const int m0 = blockIdx.x * 64;
    const int n0 = blockIdx.y * 64;
    const int bz = blockIdx.z;

    const uint4* Ag = (const uint4*)Ab;   // [1024][32]
    const uint4* Wg = (const uint4*)Wob;  // [256][32]
    #pragma unroll
    for (int i = 0; i < 2; ++i) {
        int idx = i * 256 + t;            // 0..511
        int row = idx >> 3, c8 = idx & 7;
        *(uint4*)(As_ + row * 72 + c8 * 8) = Ag[(size_t)(m0 + row) * 32 + bz * 8 + c8];
        *(uint4*)(Bs_ + row * 72 + c8 * 8) = Wg[(size_t)(n0 + row) * 32 + bz * 8 + c8];
    }
    __syncthreads();

    f32x4 acc[4] = {{0.f,0.f,0.f,0.f},{0.f,0.f,0.f,0.f},
                    {0.f,0.f,0.f,0.f},{0.f,0.f,0.f,0.f}};
    const int arow = (w << 4) + ln;
    #pragma unroll
    for (int ks = 0; ks < 2; ++ks) {
        bf16x8 a = *(const bf16x8*)(As_ + arow * 72 + ks * 32 + kg * 8);
        #pragma unroll
        for (int nf = 0; nf < 4; ++nf) {
            bf16x8 b = *(const bf16x8*)(Bs_ + (nf * 16 + ln) * 72 + ks * 32 + kg * 8);
            acc[nf] = __builtin_amdgcn_mfma_f32_16x16x32_bf16(a, b, acc[nf], 0, 0, 0);
        }
    }

    unsigned short* dst = yPb + (size_t)bz * (1024 * 256);
    #pragma unroll
    for (int nf = 0; nf < 4; ++nf) {
        #pragma unroll
        for (int r = 0; r < 4; ++r) {
            int row = m0 + w * 16 + kg * 4 + r;
            dst[(size_t)row * 256 + n0 + nf * 16 + ln] = f2bf(acc[nf][r]);
        }
    }
}

// K4: y = x + bo + sum(bf16 yPb) ; LN1 ; LN2. grid 256 x 256; 4 rows/block.
__global__ __launch_bounds__(256) void k_lnorm(
    const unsigned short* __restrict__ yPb, const float* __restrict__ x,
    const float* __restrict__ bo,
    const float* __restrict__ g1, const float* __restrict__ b1,
    const float* __restrict__ g2, const float* __restrict__ b2,
    float* __restrict__ out)
{
    __shared__ float red[4][4][2];
    const int t = threadIdx.x;
    const int r0 = blockIdx.x * 4;
    const int c = t;
    const int wid = t >> 6, lane = t & 63;

    float y[4];
    #pragma unroll
    for (int r = 0; r < 4; ++r) {
        size_t off = (size_t)(r0 + r) * 256 + c;
        y[r] = x[off] + bo[c]
             + bf2f(yPb[off]) + bf2f(yPb[262144 + off])
             + bf2f(yPb[524288 + off]) + bf2f(yPb[786432 + off]);
    }

    // LN1
    #pragma unroll
    for (int r = 0; r < 4; ++r) {
        float s = y[r], s2 = y[r] * y[r];
        #pragma unroll
        for (int off = 32; off > 0; off >>= 1) {
            s  += __shfl_xor(s, off);
            s2 += __shfl_xor(s2, off);
        }
        if (lane == 0) { red[wid][r][0] = s; red[wid][r][1] = s2; }
    }
    __syncthreads();
    float t1[4];
    #pragma unroll
    for (int r = 0; r < 4; ++r) {
        float s  = red[0][r][0] + red[1][r][0] + red[2][r][0] + red[3][r][0];
        float s2 = red[0][r][1] + red[1][r][1] + red[2][r][1] + red[3][r][1];
        float mu = s * (1.f / 256.f);
        float var = s2 * (1.f / 256.f) - mu * mu;
        float rs = rsqrtf(var + 1e-5f);
        t1[r] = (y[r] - mu) * rs * g1[c] + b1[c];
    }
    __syncthreads();

    // LN2
    #pragma unroll
    for (int r = 0; r < 4; ++r) {
        float s = t1[r], s2 = t1[r] * t1[r];
        #pragma unroll
        for (int off = 32; off > 0; off >>= 1) {
            s  += __shfl_xor(s, off);
            s2 += __shfl_xor(s2, off);
        }
        if (lane == 0) { red[wid][r][0] = s; red[wid][r][1] = s2; }
    }
    __syncthreads();
    #pragma unroll
    for (int r = 0; r < 4; ++r) {
        float s  = red[0][r][0] + red[1][r][0] + red[2][r][0] + red[3][r][0];
        float s2 = red[0][r][1] + red[1][r][1] + red[2][r][1] + red[3][r][1];
        float mu = s * (1.f / 256.f);
        float var = s2 * (1.f / 256.f) - mu * mu;
        float rs = rsqrtf(var + 1e-5f);
        out[(size_t)(r0 + r) * 256 + c] = (t1[r] - mu) * rs * g2[c] + b2[c];
    }
}

extern "C" void kernel_launch(void* const* d_in, const int* in_sizes, int n_in,
                              void* d_out, int out_size, void* d_ws, size_t ws_size,
                              hipStream_t stream)
{
    const float* x  = (const float*)d_in[0];
    const float* Wq = (const float*)d_in[1];
    const float* bq = (const float*)d_in[2];
    const float* Wk = (const float*)d_in[3];
    const float* bk = (const float*)d_in[4];   // cancels in softmax (unused)
    const float* Wv = (const float*)d_in[5];
    const float* bv = (const float*)d_in[6];
    const float* Wr = (const float*)d_in[7];
    const float* br = (const float*)d_in[8];
    const float* Wo = (const float*)d_in[9];
    const float* bo = (const float*)d_in[10];
    const float* g1 = (const float*)d_in[11];
    const float* b1 = (const float*)d_in[12];
    const float* g2 = (const float*)d_in[13];
    const float* b2 = (const float*)d_in[14];
    float* out = (float*)d_out;
    (void)bk;

    unsigned short* u = (unsigned short*)d_ws;
    unsigned short* Qb    = u;               // 1024*256
    unsigned short* Kb    = u + 262144;      // 1024*256
    unsigned short* Vtb   = u + 524288;      // 16*32*512
    unsigned short* attnb = u + 786432;      // 1024*256
    unsigned short* Wob   = u + 1048576;     // 256*256
    float* maxPart = (float*)(u + 1114112);  // [2][8][256]
    unsigned short* yPb = u + 1122304;       // [4][1024][256] bf16

    k_gemm_mfma<<<dim3(16, 17), 256, 0, stream>>>(x, Wq, Wk, Wv, Wr, Wo, bq, bv,
                                                  Qb, Kb, Vtb, Wob, maxPart);
    k_attn_mfma<<<dim3(16, 8, 2), 256, 0, stream>>>(Qb, Kb, Vtb, maxPart, br, attnb);
    k_ogemm_mfma<<<dim3(16, 4, 4), 256, 0, stream>>>(attnb, Wob, yPb);
    k_lnorm<<<256, 256, 0, stream>>>(yPb, x, bo, g1, b1, g2, b2, out);
}